// Round 1
// baseline (415.389 us; speedup 1.0000x reference)
//
#include <hip/hip_runtime.h>

#define BB 4
#define CC 64
#define HH 128
#define WW 128
#define OO 64
#define K2 9
#define OFFC 18
#define HW (HH*WW)

// ---------------- weight repack ----------------
// wt  [o][c][k] (o<64,c<64,k<9)  -> wrep[k][c][o]
// ow  [oc][c][k] (oc<18)         -> orep[c][oc*9+k]
__global__ __launch_bounds__(256) void repack_kernel(
    const float* __restrict__ wt, const float* __restrict__ ow,
    float* __restrict__ wrep, float* __restrict__ orep) {
  int i = blockIdx.x * 256 + threadIdx.x;
  if (i < OO * CC * K2) {
    int k = i % K2;
    int c = (i / K2) % CC;
    int o = i / (K2 * CC);
    wrep[(k * CC + c) * OO + o] = wt[i];
  }
  if (i < OFFC * CC * K2) {
    int k = i % K2;
    int c = (i / K2) % CC;
    int oc = i / (K2 * CC);
    orep[c * (OFFC * K2) + oc * K2 + k] = ow[i];
  }
}

// ---------------- offset conv (3x3, pad 1) ----------------
// one thread per (b,h,w); 18 accumulators
__global__ __launch_bounds__(256) void offsets_kernel(
    const float* __restrict__ x, const float* __restrict__ orep,
    const float* __restrict__ ob, float* __restrict__ offs) {
  int idx = blockIdx.x * 256 + threadIdx.x;   // 0..65535
  int w = idx & (WW - 1);
  int h = (idx >> 7) & (HH - 1);
  int b = idx >> 14;

  float acc[OFFC];
#pragma unroll
  for (int oc = 0; oc < OFFC; ++oc) acc[oc] = ob[oc];

  const float* xb = x + b * CC * HW;
  for (int c = 0; c < CC; ++c) {
    const float* xc = xb + c * HW;
    float v[9];
#pragma unroll
    for (int kh = 0; kh < 3; ++kh) {
      int hh = h + kh - 1;
#pragma unroll
      for (int kw = 0; kw < 3; ++kw) {
        int wi = w + kw - 1;
        bool ok = (hh >= 0) & (hh < HH) & (wi >= 0) & (wi < WW);
        v[kh * 3 + kw] = ok ? xc[hh * WW + wi] : 0.0f;
      }
    }
    const float* wp = orep + c * (OFFC * K2);  // wave-uniform -> s_load
#pragma unroll
    for (int oc = 0; oc < OFFC; ++oc) {
#pragma unroll
      for (int kk = 0; kk < K2; ++kk)
        acc[oc] = fmaf(v[kk], wp[oc * K2 + kk], acc[oc]);
    }
  }
#pragma unroll
  for (int oc = 0; oc < OFFC; ++oc)
    offs[((b * OFFC + oc) * HH + h) * WW + w] = acc[oc];
}

// ---------------- deformable conv main ----------------
// one thread per (b,h,w); 64 output-channel accumulators
__global__ __launch_bounds__(256, 2) void deform_kernel(
    const float* __restrict__ x, const float* __restrict__ wrep,
    const float* __restrict__ bias, const float* __restrict__ offs,
    float* __restrict__ out) {
  int idx = blockIdx.x * 256 + threadIdx.x;   // 0..65535
  int w = idx & (WW - 1);
  int h = (idx >> 7) & (HH - 1);
  int b = idx >> 14;

  float acc[OO];
#pragma unroll
  for (int o = 0; o < OO; ++o) acc[o] = bias[o];

  const float* xb = x + b * CC * HW;
  const float* offb = offs + b * OFFC * HW;

  for (int k = 0; k < K2; ++k) {
    int kh = k / 3, kw = k % 3;
    float off_h = offb[(k * HH + h) * WW + w];
    float off_w = offb[((k + K2) * HH + h) * WW + w];
    // pos in padded coords, mirror reference addition order, clip [0, Hp-1]
    float ph = (((float)kh + off_h) + (float)h) + 1.0f;
    float pw = (((float)kw + off_w) + (float)w) + 1.0f;
    ph = fminf(fmaxf(ph, 0.0f), (float)(HH + 1));
    pw = fminf(fmaxf(pw, 0.0f), (float)(WW + 1));
    int h0 = (int)floorf(ph);
    int w0 = (int)floorf(pw);
    int h1 = min(h0 + 1, HH + 1);
    int w1 = min(w0 + 1, WW + 1);
    float wh0 = (float)h1 - ph;
    float wh1 = ph - (float)h0;
    float ww0 = (float)w1 - pw;
    float ww1 = pw - (float)w0;
    // validity in padded space: rows/cols 1..128 are real data
    bool vh0 = (h0 >= 1) & (h0 <= HH);
    bool vh1 = (h1 >= 1) & (h1 <= HH);
    bool vw0 = (w0 >= 1) & (w0 <= WW);
    bool vw1 = (w1 >= 1) & (w1 <= WW);
    float c00 = (vh0 & vw0) ? wh0 * ww0 : 0.0f;
    float c01 = (vh0 & vw1) ? wh0 * ww1 : 0.0f;
    float c10 = (vh1 & vw0) ? wh1 * ww0 : 0.0f;
    float c11 = (vh1 & vw1) ? wh1 * ww1 : 0.0f;
    // clamped indices into the unpadded image (safe addresses)
    int hi0 = min(max(h0 - 1, 0), HH - 1);
    int hi1 = min(max(h1 - 1, 0), HH - 1);
    int wi0 = min(max(w0 - 1, 0), WW - 1);
    int wi1 = min(max(w1 - 1, 0), WW - 1);
    int o00 = hi0 * WW + wi0;
    int o01 = hi0 * WW + wi1;
    int o10 = hi1 * WW + wi0;
    int o11 = hi1 * WW + wi1;

#pragma unroll 2
    for (int c = 0; c < CC; ++c) {
      const float* xc = xb + c * HW;
      float v00 = xc[o00];
      float v01 = xc[o01];
      float v10 = xc[o10];
      float v11 = xc[o11];
      float val = v00 * c00 + v01 * c01 + v10 * c10 + v11 * c11;
      const float* wk = wrep + (k * CC + c) * OO;  // wave-uniform -> s_load_dwordx16
#pragma unroll
      for (int o = 0; o < OO; ++o)
        acc[o] = fmaf(val, wk[o], acc[o]);
    }
  }

  float* ob = out + b * OO * HW;
#pragma unroll
  for (int o = 0; o < OO; ++o)
    ob[o * HW + h * WW + w] = acc[o];
}

extern "C" void kernel_launch(void* const* d_in, const int* in_sizes, int n_in,
                              void* d_out, int out_size, void* d_ws, size_t ws_size,
                              hipStream_t stream) {
  const float* x        = (const float*)d_in[0];
  const float* weight   = (const float*)d_in[1];
  const float* bias     = (const float*)d_in[2];
  const float* offset_w = (const float*)d_in[3];
  const float* offset_b = (const float*)d_in[4];
  float* out = (float*)d_out;

  // ws layout
  float* offs = (float*)d_ws;                                   // 4*18*128*128 = 1,179,648 floats
  float* wrep = offs + (size_t)BB * OFFC * HW;                  // 36,864 floats
  float* orep = wrep + (size_t)OO * CC * K2;                    // 10,368 floats

  repack_kernel<<<(OO * CC * K2 + 255) / 256, 256, 0, stream>>>(weight, offset_w, wrep, orep);
  offsets_kernel<<<(BB * HW) / 256, 256, 0, stream>>>(x, orep, offset_b, offs);
  deform_kernel<<<(BB * HW) / 256, 256, 0, stream>>>(x, wrep, bias, offs, out);
}

// Round 2
// 176.529 us; speedup vs baseline: 2.3531x; 2.3531x over previous
//
#include <hip/hip_runtime.h>

#define BB 4
#define CC 64
#define HH 128
#define WW 128
#define OO 64
#define K2 9
#define HP 131          // padded rows allocated (indices 0..130)
#define WP 132          // padded row stride  (indices 0..130 used)
#define HW (HH*WW)
#define OFFSTR 20       // floats per pixel row in offs buffer
#define ASTR 72         // bf16 elems per LDS A-tile row (64 + 8 pad)

typedef __attribute__((ext_vector_type(8))) short short8;
typedef __attribute__((ext_vector_type(4))) float f32x4;

__device__ __forceinline__ unsigned int f2b(float f) {  // RNE float->bf16 bits
  unsigned int u = __float_as_uint(f);
  return (u + 0x7fffu + ((u >> 16) & 1u)) >> 16;
}

// ---------------- pad + bf16 cast: x[4][64][128][128] -> xpad[4*64][131][132], zeros elsewhere ----------------
__global__ __launch_bounds__(256) void pad_kernel(const float* __restrict__ x,
                                                  ushort* __restrict__ xpad) {
  int i = blockIdx.x * 256 + threadIdx.x;
  if (i >= BB * CC * HP * WP) return;
  int wp = i % WP;
  int t = i / WP;
  int hp = t % HP;
  int bc = t / HP;
  ushort v = 0;
  if (hp >= 1 && hp <= HH && wp >= 1 && wp <= WW)
    v = (ushort)f2b(x[(size_t)bc * HW + (hp - 1) * WW + (wp - 1)]);
  xpad[i] = v;
}

// ---------------- weight repack to bf16, K-index = kk*64+c ----------------
// wb [o][kk*64+c]  (64x576), owb [oc][kk*64+c] (32x576, rows 18..31 zero)
__global__ __launch_bounds__(256) void repackw_kernel(const float* __restrict__ wt,
                                                      const float* __restrict__ ow,
                                                      ushort* __restrict__ wb,
                                                      ushort* __restrict__ owb) {
  int i = blockIdx.x * 256 + threadIdx.x;
  if (i < OO * 576) {
    int o = i / 576, r = i % 576;
    int kk = r >> 6, c = r & 63;
    wb[i] = (ushort)f2b(wt[(o * CC + c) * K2 + kk]);
  } else if (i < OO * 576 + 32 * 576) {
    int j = i - OO * 576;
    int oc = j / 576, r = j % 576;
    int kk = r >> 6, c = r & 63;
    owb[j] = (oc < 18) ? (ushort)f2b(ow[(oc * CC + c) * K2 + kk]) : (ushort)0;
  }
}

// ---------------- offset conv as MFMA GEMM ----------------
// block = 256 thr (4 waves), M-tile = 128 pixels = one (b,h) row; N=32 (18 valid), K=576
__global__ __launch_bounds__(256) void offs_gemm(const ushort* __restrict__ xpad,
                                                 const ushort* __restrict__ owb,
                                                 const float* __restrict__ ob,
                                                 float* __restrict__ offs) {
  __shared__ __align__(16) ushort As[128 * ASTR];
  int tid = threadIdx.x, blk = blockIdx.x;
  int b = blk >> 7, h = blk & 127;
  int p = tid & 127, chb = (tid >> 7) * 32;
  int wave = tid >> 6, lane = tid & 63, lm = lane & 15, lq = lane >> 4;

  f32x4 acc[2][2];
#pragma unroll
  for (int mt = 0; mt < 2; ++mt)
#pragma unroll
    for (int nt = 0; nt < 2; ++nt) acc[mt][nt] = (f32x4)0.0f;

  const ushort* xb = xpad + ((size_t)b * CC + chb) * (HP * WP);

#pragma unroll
  for (int kk = 0; kk < 9; ++kk) {
    int kh = kk / 3, kw = kk % 3;
    const ushort* src = xb + (size_t)(h + kh) * WP + (p + kw);
    ushort* dst = &As[p * ASTR + chb];
#pragma unroll
    for (int c8 = 0; c8 < 4; ++c8) {
      unsigned int pk[4];
#pragma unroll
      for (int j = 0; j < 4; ++j) {
        unsigned int lo = src[0]; src += HP * WP;
        unsigned int hi = src[0]; src += HP * WP;
        pk[j] = lo | (hi << 16);
      }
      *(uint4*)(dst + c8 * 8) = make_uint4(pk[0], pk[1], pk[2], pk[3]);
    }
    __syncthreads();
#pragma unroll
    for (int s = 0; s < 2; ++s) {
      short8 a0 = *(const short8*)&As[(wave * 32 + lm) * ASTR + s * 32 + lq * 8];
      short8 a1 = *(const short8*)&As[(wave * 32 + 16 + lm) * ASTR + s * 32 + lq * 8];
#pragma unroll
      for (int nt = 0; nt < 2; ++nt) {
        short8 bf = *(const short8*)&owb[(nt * 16 + lm) * 576 + kk * 64 + s * 32 + lq * 8];
        acc[0][nt] = __builtin_amdgcn_mfma_f32_16x16x32_bf16(a0, bf, acc[0][nt], 0, 0, 0);
        acc[1][nt] = __builtin_amdgcn_mfma_f32_16x16x32_bf16(a1, bf, acc[1][nt], 0, 0, 0);
      }
    }
    __syncthreads();
  }
  // epilogue: D row = lq*4+r (pixel within 16-tile), col = lm (oc)
#pragma unroll
  for (int nt = 0; nt < 2; ++nt) {
    int oc = nt * 16 + lm;
    if (oc < 18) {
      float bv = ob[oc];
#pragma unroll
      for (int mt = 0; mt < 2; ++mt) {
#pragma unroll
        for (int r = 0; r < 4; ++r) {
          int pix = blk * 128 + wave * 32 + mt * 16 + lq * 4 + r;
          offs[(size_t)pix * OFFSTR + oc] = acc[mt][nt][r] + bv;
        }
      }
    }
  }
}

// ---------------- deformable conv main as MFMA GEMM ----------------
// block = 256 thr (4 waves), M-tile = 128 pixels = one (b,h) row; N=64, K=576
__global__ __launch_bounds__(256) void deform_gemm(const ushort* __restrict__ xpad,
                                                   const ushort* __restrict__ wb,
                                                   const float* __restrict__ bias,
                                                   const float* __restrict__ offs,
                                                   float* __restrict__ out) {
  __shared__ __align__(16) ushort As[128 * ASTR];
  int tid = threadIdx.x, blk = blockIdx.x;
  int b = blk >> 7, h = blk & 127;
  int p = tid & 127, chb = (tid >> 7) * 32;
  int wave = tid >> 6, lane = tid & 63, lm = lane & 15, lq = lane >> 4;

  f32x4 acc[2][4];
#pragma unroll
  for (int mt = 0; mt < 2; ++mt)
#pragma unroll
    for (int nt = 0; nt < 4; ++nt) acc[mt][nt] = (f32x4)0.0f;

  // preload this pixel's 18 offsets (20-float padded row)
  float orow[OFFSTR];
  {
    const float* orp = offs + (size_t)(blk * 128 + p) * OFFSTR;
#pragma unroll
    for (int q = 0; q < 5; ++q) *(float4*)&orow[q * 4] = *(const float4*)(orp + q * 4);
  }

  const ushort* xb = xpad + ((size_t)b * CC + chb) * (HP * WP);

#pragma unroll
  for (int kk = 0; kk < 9; ++kk) {
    int kh = kk / 3, kw = kk % 3;
    // padded coords, mirror reference op order; clip to [0, 129]
    float ph = (((float)kh + orow[kk]) + (float)h) + 1.0f;
    float pw = (((float)kw + orow[kk + 9]) + (float)p) + 1.0f;
    ph = fminf(fmaxf(ph, 0.0f), 129.0f);
    pw = fminf(fmaxf(pw, 0.0f), 129.0f);
    float fh0 = floorf(ph), fw0 = floorf(pw);
    int h0 = (int)fh0, w0 = (int)fw0;        // 0..129; h0+1,w0+1 <= 130 in-bounds of pad
    float wh1 = ph - fh0, ww1 = pw - fw0;
    float wh0 = 1.0f - wh1, ww0 = 1.0f - ww1;

    const ushort* srow = xb + (size_t)h0 * WP + w0;
    ushort* dst = &As[p * ASTR + chb];
#pragma unroll
    for (int c8 = 0; c8 < 4; ++c8) {
      unsigned int pk[4];
#pragma unroll
      for (int j = 0; j < 4; ++j) {
        unsigned int r0, r1, r2, r3;
        __builtin_memcpy(&r0, srow, 4);          // (h0,w0),(h0,w0+1) bf16 pair
        __builtin_memcpy(&r1, srow + WP, 4);     // (h1,w0),(h1,w0+1)
        srow += HP * WP;
        __builtin_memcpy(&r2, srow, 4);
        __builtin_memcpy(&r3, srow + WP, 4);
        srow += HP * WP;
        float v00 = __uint_as_float(r0 << 16);
        float v01 = __uint_as_float(r0 & 0xffff0000u);
        float v10 = __uint_as_float(r1 << 16);
        float v11 = __uint_as_float(r1 & 0xffff0000u);
        float val0 = (v00 * ww0 + v01 * ww1) * wh0 + (v10 * ww0 + v11 * ww1) * wh1;
        float u00 = __uint_as_float(r2 << 16);
        float u01 = __uint_as_float(r2 & 0xffff0000u);
        float u10 = __uint_as_float(r3 << 16);
        float u11 = __uint_as_float(r3 & 0xffff0000u);
        float val1 = (u00 * ww0 + u01 * ww1) * wh0 + (u10 * ww0 + u11 * ww1) * wh1;
        pk[j] = f2b(val0) | (f2b(val1) << 16);
      }
      *(uint4*)(dst + c8 * 8) = make_uint4(pk[0], pk[1], pk[2], pk[3]);
    }
    __syncthreads();
#pragma unroll
    for (int s = 0; s < 2; ++s) {
      short8 a0 = *(const short8*)&As[(wave * 32 + lm) * ASTR + s * 32 + lq * 8];
      short8 a1 = *(const short8*)&As[(wave * 32 + 16 + lm) * ASTR + s * 32 + lq * 8];
#pragma unroll
      for (int nt = 0; nt < 4; ++nt) {
        short8 bf = *(const short8*)&wb[(nt * 16 + lm) * 576 + kk * 64 + s * 32 + lq * 8];
        acc[0][nt] = __builtin_amdgcn_mfma_f32_16x16x32_bf16(a0, bf, acc[0][nt], 0, 0, 0);
        acc[1][nt] = __builtin_amdgcn_mfma_f32_16x16x32_bf16(a1, bf, acc[1][nt], 0, 0, 0);
      }
    }
    __syncthreads();
  }

  // epilogue: o = nt*16+lm, pixel w = wave*32 + mt*16 + lq*4 + r
#pragma unroll
  for (int nt = 0; nt < 4; ++nt) {
    int o = nt * 16 + lm;
    float bv = bias[o];
#pragma unroll
    for (int mt = 0; mt < 2; ++mt) {
#pragma unroll
      for (int r = 0; r < 4; ++r) {
        int w = wave * 32 + mt * 16 + lq * 4 + r;
        out[((size_t)(b * OO + o) * HH + h) * WW + w] = acc[mt][nt][r] + bv;
      }
    }
  }
}

extern "C" void kernel_launch(void* const* d_in, const int* in_sizes, int n_in,
                              void* d_out, int out_size, void* d_ws, size_t ws_size,
                              hipStream_t stream) {
  const float* x        = (const float*)d_in[0];
  const float* weight   = (const float*)d_in[1];
  const float* bias     = (const float*)d_in[2];
  const float* offset_w = (const float*)d_in[3];
  const float* offset_b = (const float*)d_in[4];
  float* out = (float*)d_out;

  // ws layout (all 16B-aligned)
  ushort* xpad = (ushort*)d_ws;                              // 4*64*131*132 = 4,424,448 ushorts
  ushort* wb   = xpad + (size_t)BB * CC * HP * WP;           // 64*576
  ushort* owb  = wb + (size_t)OO * 576;                      // 32*576
  float*  offs = (float*)(owb + (size_t)32 * 576);           // 65536*20 floats

  pad_kernel<<<(BB * CC * HP * WP + 255) / 256, 256, 0, stream>>>(x, xpad);
  repackw_kernel<<<(OO * 576 + 32 * 576 + 255) / 256, 256, 0, stream>>>(weight, offset_w, wb, owb);
  offs_gemm<<<BB * HH, 256, 0, stream>>>(xpad, owb, offset_b, offs);
  deform_gemm<<<BB * HH, 256, 0, stream>>>(xpad, wb, bias, offs, out);
}

// Round 3
// 165.138 us; speedup vs baseline: 2.5154x; 1.0690x over previous
//
#include <hip/hip_runtime.h>

#define BB 4
#define CC 64
#define OO 64
#define HH 128
#define WW 128
#define HP 131          // padded rows allocated (indices 0..130 valid)
#define WP 132          // padded row stride
#define PS (HP*WP)      // pair-plane stride in uints (17292)
#define HW (HH*WW)
#define OFFSTR 20       // floats per pixel in offs buffer (9 float2 pairs + pad)

typedef __attribute__((ext_vector_type(8))) short short8;
typedef __attribute__((ext_vector_type(4))) float f32x4;

__device__ __forceinline__ unsigned f2b(float f) {  // RNE float->bf16 bits
  unsigned u = __float_as_uint(f);
  return (u + 0x7fffu + ((u >> 16) & 1u)) >> 16;
}
__device__ __forceinline__ float blo(unsigned r) { return __uint_as_float(r << 16); }
__device__ __forceinline__ float bhi(unsigned r) { return __uint_as_float(r & 0xffff0000u); }

// ---------------- pad + bf16 + channel-pair interleave ----------------
// xpad2[(b*32+c2)][hp][wp] = pack(bf16(x[b][2c2][hp-1][wp-1]), bf16(x[b][2c2+1][hp-1][wp-1]))
__global__ __launch_bounds__(256) void pad_kernel(const float* __restrict__ x,
                                                  unsigned* __restrict__ xpad2) {
  int i = blockIdx.x * 256 + threadIdx.x;
  if (i >= BB * 32 * PS) return;
  int wp = i % WP;
  int t = i / WP;
  int hp = t % HP;
  int p2 = t / HP;                 // b*32 + c2
  int b = p2 >> 5, c2 = p2 & 31;
  unsigned v = 0;
  if (hp >= 1 && hp <= HH && wp >= 1 && wp <= WW) {
    const float* src = x + (((size_t)(b * CC + 2 * c2)) * HH + (hp - 1)) * WW + (wp - 1);
    v = f2b(src[0]) | (f2b(src[HW]) << 16);
  }
  xpad2[i] = v;
}

// ---------------- weight repack to bf16, K-index = kk*64+c ----------------
__global__ __launch_bounds__(256) void repackw_kernel(const float* __restrict__ wt,
                                                      const float* __restrict__ ow,
                                                      ushort* __restrict__ wb,
                                                      ushort* __restrict__ owb) {
  int i = blockIdx.x * 256 + threadIdx.x;
  if (i < OO * 576) {
    int o = i / 576, r = i % 576;
    int kk = r >> 6, c = r & 63;
    wb[i] = (ushort)f2b(wt[(o * CC + c) * 9 + kk]);
  } else if (i < OO * 576 + 32 * 576) {
    int j = i - OO * 576;
    int oc = j / 576, r = j % 576;
    int kk = r >> 6, c = r & 63;
    owb[j] = (oc < 18) ? (ushort)f2b(ow[(oc * CC + c) * 9 + kk]) : (ushort)0;
  }
}

// ---------------- offset conv: register-direct MFMA, no LDS ----------------
// wave = 16 pixels (one row segment), N=32 (18 valid), K=576
__global__ __launch_bounds__(256, 4) void offs_gemm(const unsigned* __restrict__ xpad2,
                                                    const ushort* __restrict__ owb,
                                                    const float* __restrict__ ob,
                                                    float* __restrict__ offs) {
  int tid = threadIdx.x;
  int wgid = blockIdx.x * 4 + (tid >> 6);
  int lane = tid & 63, lm = lane & 15, lq = lane >> 4;
  int base = wgid * 16;
  int b = base >> 14, h = (base >> 7) & 127, wt = base & 127;
  int w = wt + lm;

  f32x4 acc[2];
  acc[0] = (f32x4)0.0f; acc[1] = (f32x4)0.0f;

  const unsigned* xb = xpad2 + ((size_t)b * 32 + lq * 4) * PS;

#pragma unroll 1
  for (int kh = 0; kh < 3; ++kh) {
#pragma unroll 1
    for (int kw = 0; kw < 3; ++kw) {
      int kk = kh * 3 + kw;
      const unsigned* p0 = xb + (size_t)(h + kh) * WP + (w + kw);
#pragma unroll
      for (int s = 0; s < 2; ++s) {
        union { unsigned u[4]; short8 v; } a;
#pragma unroll
        for (int t = 0; t < 4; ++t)
          a.u[t] = p0[(size_t)(s * 16 + t) * PS];
#pragma unroll
        for (int nt = 0; nt < 2; ++nt) {
          short8 bf = *(const short8*)&owb[(size_t)(nt * 16 + lm) * 576 + kk * 64 + s * 32 + lq * 8];
          acc[nt] = __builtin_amdgcn_mfma_f32_16x16x32_bf16(a.v, bf, acc[nt], 0, 0, 0);
        }
      }
    }
  }
  // D: row = lq*4+r (pixel), col = lm (oc). offs pair layout: [pix][tap*2 + {h:0,w:1}]
#pragma unroll
  for (int nt = 0; nt < 2; ++nt) {
    int oc = nt * 16 + lm;
    if (oc < 18) {
      float bv = ob[oc];
      int idx = (oc < 9) ? (oc * 2) : ((oc - 9) * 2 + 1);
#pragma unroll
      for (int r = 0; r < 4; ++r) {
        int pix = base + lq * 4 + r;
        offs[(size_t)pix * OFFSTR + idx] = acc[nt][r] + bv;
      }
    }
  }
}

// ---------------- deformable conv: register-direct MFMA, no LDS ----------------
// wave = 16 pixels, N=64, K=576; lane computes its own A-fragment via bilinear lerp
__global__ __launch_bounds__(256, 4) void deform_gemm(const unsigned* __restrict__ xpad2,
                                                      const ushort* __restrict__ wb,
                                                      const float* __restrict__ bias,
                                                      const float* __restrict__ offs,
                                                      float* __restrict__ out) {
  int tid = threadIdx.x;
  int wgid = blockIdx.x * 4 + (tid >> 6);
  int lane = tid & 63, lm = lane & 15, lq = lane >> 4;
  int base = wgid * 16;
  int b = base >> 14, h = (base >> 7) & 127, wt = base & 127;
  int w = wt + lm;
  int pix = base + lm;

  f32x4 acc[4];
#pragma unroll
  for (int nt = 0; nt < 4; ++nt) acc[nt] = (f32x4)0.0f;

  const unsigned* xb = xpad2 + ((size_t)b * 32 + lq * 4) * PS;
  const float* op = offs + (size_t)pix * OFFSTR;

#pragma unroll 1
  for (int kh = 0; kh < 3; ++kh) {
#pragma unroll 1
    for (int kw = 0; kw < 3; ++kw) {
      int kk = kh * 3 + kw;
      float2 off = *(const float2*)(op + kk * 2);
      // padded coords, mirror reference op order; clip to [0, Hp-1]=129
      float ph = (((float)kh + off.x) + (float)h) + 1.0f;
      float pw = (((float)kw + off.y) + (float)w) + 1.0f;
      ph = fminf(fmaxf(ph, 0.0f), 129.0f);
      pw = fminf(fmaxf(pw, 0.0f), 129.0f);
      float fh0 = floorf(ph), fw0 = floorf(pw);
      int h0 = (int)fh0, w0 = (int)fw0;          // 0..129; +1 row/col stays in-bounds
      float wh1 = ph - fh0, ww1 = pw - fw0;
      float wh0 = 1.0f - wh1, ww0 = 1.0f - ww1;
      const unsigned* p00 = xb + (size_t)h0 * WP + w0;
#pragma unroll
      for (int s = 0; s < 2; ++s) {
        union { unsigned u[4]; short8 v; } a;
#pragma unroll
        for (int t = 0; t < 4; ++t) {
          const unsigned* pc = p00 + (size_t)(s * 16 + t) * PS;
          unsigned q00 = pc[0], q01 = pc[1];
          unsigned q10 = pc[WP], q11 = pc[WP + 1];
          float vA = (blo(q00) * ww0 + blo(q01) * ww1) * wh0
                   + (blo(q10) * ww0 + blo(q11) * ww1) * wh1;
          float vB = (bhi(q00) * ww0 + bhi(q01) * ww1) * wh0
                   + (bhi(q10) * ww0 + bhi(q11) * ww1) * wh1;
          a.u[t] = f2b(vA) | (f2b(vB) << 16);
        }
#pragma unroll
        for (int nt = 0; nt < 4; ++nt) {
          short8 bf = *(const short8*)&wb[(size_t)(nt * 16 + lm) * 576 + kk * 64 + s * 32 + lq * 8];
          acc[nt] = __builtin_amdgcn_mfma_f32_16x16x32_bf16(a.v, bf, acc[nt], 0, 0, 0);
        }
      }
    }
  }

  // epilogue: o = nt*16+lm; pixels lq*4..lq*4+3 are 4 consecutive w -> float4 store
#pragma unroll
  for (int nt = 0; nt < 4; ++nt) {
    int o = nt * 16 + lm;
    float bv = bias[o];
    float4 st = make_float4(acc[nt][0] + bv, acc[nt][1] + bv, acc[nt][2] + bv, acc[nt][3] + bv);
    *(float4*)(out + ((size_t)(b * OO + o) * HH + h) * WW + wt + lq * 4) = st;
  }
}

extern "C" void kernel_launch(void* const* d_in, const int* in_sizes, int n_in,
                              void* d_out, int out_size, void* d_ws, size_t ws_size,
                              hipStream_t stream) {
  const float* x        = (const float*)d_in[0];
  const float* weight   = (const float*)d_in[1];
  const float* bias     = (const float*)d_in[2];
  const float* offset_w = (const float*)d_in[3];
  const float* offset_b = (const float*)d_in[4];
  float* out = (float*)d_out;

  // ws layout (16B-aligned blocks)
  unsigned* xpad2 = (unsigned*)d_ws;                       // 128 * 17292 uints = 8,853,504 B
  ushort* wb  = (ushort*)(xpad2 + (size_t)BB * 32 * PS);   // 64*576 ushorts
  ushort* owb = wb + (size_t)OO * 576;                     // 32*576 ushorts
  float* offs = (float*)(owb + (size_t)32 * 576);          // 65536*20 floats

  pad_kernel<<<(BB * 32 * PS + 255) / 256, 256, 0, stream>>>(x, xpad2);
  repackw_kernel<<<(OO * 576 + 32 * 576 + 255) / 256, 256, 0, stream>>>(weight, offset_w, wb, owb);
  offs_gemm<<<1024, 256, 0, stream>>>(xpad2, owb, offset_b, offs);
  deform_gemm<<<1024, 256, 0, stream>>>(xpad2, wb, bias, offs, out);
}